// Round 4
// baseline (223.863 us; speedup 1.0000x reference)
//
#include <hip/hip_runtime.h>
#include <math.h>

#define N_NODES 1024
#define F_IN 256
#define HD 256
#define DZ 64
#define MH 128

// ---------- fused preprocessing: degree+hist (LDS atomics), scan, dinv, CSR fill ----------
// One block, 1024 threads. Replaces memset + deg_hist + dinv_scan + fill (4 dispatches).
__global__ __launch_bounds__(1024) void preprocess_kernel(
        const int* __restrict__ ei, const float* __restrict__ ew,
        float* __restrict__ dinv_g, int* __restrict__ start_g,
        int* __restrict__ srcrow, float* __restrict__ enorm, int E) {
    __shared__ float degs[N_NODES];
    __shared__ int   cnt[N_NODES];
    __shared__ int   scan[N_NODES];
    __shared__ float dinvs[N_NODES];
    __shared__ int   cur[N_NODES];
    int t = threadIdx.x;
    degs[t] = 0.f; cnt[t] = 0;
    __syncthreads();
    for (int e = t; e < E; e += 1024) {
        int c = ei[E + e];
        atomicAdd(&degs[c], ew[e]);
        atomicAdd(&cnt[c], 1);
    }
    __syncthreads();
    float di = rsqrtf(degs[t] + 1.0f);    // +1 = self loop, always > 0
    dinvs[t] = di;
    dinv_g[t] = di;
    scan[t] = cnt[t];
    __syncthreads();
    for (int off = 1; off < N_NODES; off <<= 1) {
        int v = (t >= off) ? scan[t - off] : 0;
        __syncthreads();
        scan[t] += v;
        __syncthreads();
    }
    int st = scan[t] - cnt[t];            // exclusive prefix
    cur[t] = st;
    start_g[t] = st;
    if (t == N_NODES - 1) start_g[N_NODES] = scan[t];
    __syncthreads();
    for (int e = t; e < E; e += 1024) {
        int r = ei[e], c = ei[E + e];
        int idx = atomicAdd(&cur[c], 1);
        srcrow[idx] = r;
        enorm[idx] = dinvs[r] * ew[e] * dinvs[c];
    }
}

// ---------- GEMM: 32x32 tile, 256 threads, 2x2 per thread, K-step 16 (256 blocks) ----------
__global__ __launch_bounds__(256) void gemm32(const float* __restrict__ A,
        const float* __restrict__ B, float* __restrict__ C, int K, int Nc) {
    __shared__ float As[16][36];
    __shared__ float Bs[16][36];
    int tid = threadIdx.x;
    int tx = tid & 15, ty = tid >> 4;
    int m0 = blockIdx.y * 32, n0 = blockIdx.x * 32;
    float a00 = 0.f, a01 = 0.f, a10 = 0.f, a11 = 0.f;
    for (int k0 = 0; k0 < K; k0 += 16) {
#pragma unroll
        for (int u = 0; u < 2; ++u) {
            int idx = tid + u * 256;
            int r = idx >> 4, kk = idx & 15;
            As[kk][r] = A[(m0 + r) * K + k0 + kk];
            int kb = idx >> 5, c = idx & 31;
            Bs[kb][c] = B[(k0 + kb) * Nc + n0 + c];
        }
        __syncthreads();
#pragma unroll
        for (int kk = 0; kk < 16; ++kk) {
            float2 a = *(float2*)&As[kk][ty * 2];
            float2 b = *(float2*)&Bs[kk][tx * 2];
            a00 += a.x * b.x; a01 += a.x * b.y;
            a10 += a.y * b.x; a11 += a.y * b.y;
        }
        __syncthreads();
    }
    int row = m0 + ty * 2, col = n0 + tx * 2;
    C[row * Nc + col]           = a00;
    C[row * Nc + col + 1]       = a01;
    C[(row + 1) * Nc + col]     = a10;
    C[(row + 1) * Nc + col + 1] = a11;
}

// ---------- fused: h1[node] = relu(gather(hlin1)+b1) ; hlin2[node] = h1[node] @ W2 ----------
__global__ __launch_bounds__(256) void gather_gemm2_kernel(
        const int* __restrict__ start, const int* __restrict__ srcrow,
        const float* __restrict__ enorm, const float* __restrict__ dinv,
        const float* __restrict__ hlin1, const float* __restrict__ b1,
        const float* __restrict__ W2, float* __restrict__ hlin2) {
    __shared__ float h1s[HD];
    __shared__ float part[4][DZ];
    int node = blockIdx.x;
    int f = threadIdx.x;
    int s = start[node], e = start[node + 1];
    float di = dinv[node];
    float acc0 = di * di * hlin1[node * HD + f];      // self loop
    float acc1 = 0.f;
    int k = s;
    for (; k + 1 < e; k += 2) {
        acc0 += enorm[k]     * hlin1[srcrow[k]     * HD + f];
        acc1 += enorm[k + 1] * hlin1[srcrow[k + 1] * HD + f];
    }
    if (k < e) acc0 += enorm[k] * hlin1[srcrow[k] * HD + f];
    h1s[f] = fmaxf(acc0 + acc1 + b1[f], 0.f);
    __syncthreads();
    int c = f & 63, q = f >> 6;
    float p = 0.f;
#pragma unroll
    for (int kk = 0; kk < 64; ++kk)
        p += h1s[q * 64 + kk] * W2[(q * 64 + kk) * DZ + c];
    part[q][c] = p;
    __syncthreads();
    if (f < 64)
        hlin2[node * DZ + f] = part[0][f] + part[1][f] + part[2][f] + part[3][f];
}

// ---------- fused: z = gather(hlin2)+b2 ; Adec = z@dW1[:64]+db1 ; Bdec = z@dW1[64:] ----------
__global__ __launch_bounds__(256) void gather_dec_kernel(
        const int* __restrict__ start, const int* __restrict__ srcrow,
        const float* __restrict__ enorm, const float* __restrict__ dinv,
        const float* __restrict__ hlin2, const float* __restrict__ b2,
        const float* __restrict__ dW1, const float* __restrict__ db1,
        float* __restrict__ z, float* __restrict__ Adec, float* __restrict__ Bdec) {
    __shared__ float zs[4][DZ];
    int tid = threadIdx.x;
    int nl = tid >> 6, f = tid & 63;
    int node = blockIdx.x * 4 + nl;
    int s = start[node], e = start[node + 1];
    float di = dinv[node];
    float acc0 = di * di * hlin2[node * DZ + f];
    float acc1 = 0.f;
    int k = s;
    for (; k + 1 < e; k += 2) {
        acc0 += enorm[k]     * hlin2[srcrow[k]     * DZ + f];
        acc1 += enorm[k + 1] * hlin2[srcrow[k + 1] * DZ + f];
    }
    if (k < e) acc0 += enorm[k] * hlin2[srcrow[k] * DZ + f];
    float acc = acc0 + acc1 + b2[f];
    z[node * DZ + f] = acc;
    zs[nl][f] = acc;
    __syncthreads();
    int half = tid >> 7;
    int c = tid & 127;
    float o0 = 0.f, o1 = 0.f, o2 = 0.f, o3 = 0.f;
#pragma unroll
    for (int kk = 0; kk < 64; ++kk) {
        float w = dW1[(half * 64 + kk) * MH + c];
        o0 += zs[0][kk] * w;
        o1 += zs[1][kk] * w;
        o2 += zs[2][kk] * w;
        o3 += zs[3][kk] * w;
    }
    float bb = half ? 0.f : db1[c];
    float* outbuf = half ? Bdec : Adec;
    int n0 = blockIdx.x * 4;
    outbuf[(n0 + 0) * MH + c] = o0 + bb;
    outbuf[(n0 + 1) * MH + c] = o1 + bb;
    outbuf[(n0 + 2) * MH + c] = o2 + bb;
    outbuf[(n0 + 3) * MH + c] = o3 + bb;
}

// ---------- decoder: 32x32 tile, 2x2 per thread ----------
__global__ __launch_bounds__(256) void decoder_kernel(
        const float* __restrict__ Adec, const float* __restrict__ Bdec,
        const float* __restrict__ dW2, const float* __restrict__ db2,
        float* __restrict__ adj) {
    __shared__ float As[32][132];
    __shared__ float Bs[32][132];
    __shared__ float wv[128];
    int tx = threadIdx.x, ty = threadIdx.y;
    int tid = ty * 16 + tx;
    int i0 = blockIdx.y * 32, j0 = blockIdx.x * 32;
    for (int t = tid; t < 32 * 32; t += 256) {
        int r = t >> 5, hh = (t & 31) << 2;
        *(float4*)&As[r][hh] = *(const float4*)&Adec[(i0 + r) * MH + hh];
        *(float4*)&Bs[r][hh] = *(const float4*)&Bdec[(j0 + r) * MH + hh];
    }
    if (tid < 32) *(float4*)&wv[tid * 4] = *(const float4*)&dW2[tid * 4];
    __syncthreads();
    float s00 = 0.f, s01 = 0.f, s10 = 0.f, s11 = 0.f;
#pragma unroll
    for (int h = 0; h < 128; h += 4) {
        float4 a0 = *(float4*)&As[ty * 2][h];
        float4 a1 = *(float4*)&As[ty * 2 + 1][h];
        float4 b0 = *(float4*)&Bs[tx * 2][h];
        float4 b1 = *(float4*)&Bs[tx * 2 + 1][h];
        float4 w = *(float4*)&wv[h];
        s00 += fmaxf(a0.x + b0.x, 0.f) * w.x + fmaxf(a0.y + b0.y, 0.f) * w.y
             + fmaxf(a0.z + b0.z, 0.f) * w.z + fmaxf(a0.w + b0.w, 0.f) * w.w;
        s01 += fmaxf(a0.x + b1.x, 0.f) * w.x + fmaxf(a0.y + b1.y, 0.f) * w.y
             + fmaxf(a0.z + b1.z, 0.f) * w.z + fmaxf(a0.w + b1.w, 0.f) * w.w;
        s10 += fmaxf(a1.x + b0.x, 0.f) * w.x + fmaxf(a1.y + b0.y, 0.f) * w.y
             + fmaxf(a1.z + b0.z, 0.f) * w.z + fmaxf(a1.w + b0.w, 0.f) * w.w;
        s11 += fmaxf(a1.x + b1.x, 0.f) * w.x + fmaxf(a1.y + b1.y, 0.f) * w.y
             + fmaxf(a1.z + b1.z, 0.f) * w.z + fmaxf(a1.w + b1.w, 0.f) * w.w;
    }
    float b2v = db2[0];
    int ri = i0 + ty * 2, cj = j0 + tx * 2;
    adj[ri * N_NODES + cj]           = 1.f / (1.f + __expf(-(s00 + b2v)));
    adj[ri * N_NODES + cj + 1]       = 1.f / (1.f + __expf(-(s01 + b2v)));
    adj[(ri + 1) * N_NODES + cj]     = 1.f / (1.f + __expf(-(s10 + b2v)));
    adj[(ri + 1) * N_NODES + cj + 1] = 1.f / (1.f + __expf(-(s11 + b2v)));
}

extern "C" void kernel_launch(void* const* d_in, const int* in_sizes, int n_in,
                              void* d_out, int out_size, void* d_ws, size_t ws_size,
                              hipStream_t stream) {
    const float* x   = (const float*)d_in[0];
    const int*   ei  = (const int*)  d_in[1];
    const float* ew  = (const float*)d_in[2];
    const float* W1  = (const float*)d_in[3];
    const float* b1  = (const float*)d_in[4];
    const float* W2  = (const float*)d_in[5];
    const float* b2  = (const float*)d_in[6];
    const float* dW1 = (const float*)d_in[7];
    const float* db1 = (const float*)d_in[8];
    const float* dW2 = (const float*)d_in[9];
    const float* db2 = (const float*)d_in[10];
    int E = in_sizes[2];

    // workspace layout
    float* ws    = (float*)d_ws;
    float* dinv  = ws;                         // 1024 f
    int*   start = (int*)(ws + N_NODES);       // 1025 i (+pad)
    int*   srcrow= start + N_NODES + 32;       // E i
    float* enorm = (float*)(srcrow + E);       // E f
    float* hlin1 = enorm + E;                  // 1024*256
    float* hlin2 = hlin1 + N_NODES * HD;       // 1024*64
    float* Adec  = hlin2 + N_NODES * DZ;       // 1024*128
    float* Bdec  = Adec + N_NODES * MH;        // 1024*128

    float* z   = (float*)d_out;                // 1024*64
    float* adj = z + N_NODES * DZ;             // 1024*1024

    preprocess_kernel<<<1, 1024, 0, stream>>>(ei, ew, dinv, start, srcrow, enorm, E);

    // hlin1 = x @ W1   (256 blocks)
    gemm32<<<dim3(HD / 32, N_NODES / 32), dim3(256), 0, stream>>>(
        x, W1, hlin1, F_IN, HD);

    // hlin2 = relu(gather(hlin1)+b1) @ W2   (one block per node)
    gather_gemm2_kernel<<<N_NODES, 256, 0, stream>>>(
        start, srcrow, enorm, dinv, hlin1, b1, W2, hlin2);

    // z = gather(hlin2)+b2 ; Adec = z@dW1[:64]+db1 ; Bdec = z@dW1[64:]
    gather_dec_kernel<<<N_NODES / 4, 256, 0, stream>>>(
        start, srcrow, enorm, dinv, hlin2, b2, dW1, db1, z, Adec, Bdec);

    decoder_kernel<<<dim3(N_NODES / 32, N_NODES / 32), dim3(16, 16), 0, stream>>>(
        Adec, Bdec, dW2, db2, adj);
}